// Round 2
// 782.892 us; speedup vs baseline: 1.2689x; 1.2689x over previous
//
#include <hip/hip_runtime.h>
#include <hip/hip_bf16.h>

using bf16 = __hip_bfloat16;

__device__ __forceinline__ float b2f(bf16 v) { return __bfloat162float(v); }
__device__ __forceinline__ bf16 f2b(float f) { return __float2bfloat16(f); }
__device__ __forceinline__ float u2f(unsigned short u) {
    return __uint_as_float(((unsigned)u) << 16);
}

#define B 8
#define CIN 256
#define HW 4096
#define QKV_CH 768
#define PROJ_IN 512
#define PROJ_OUT 256
#define NPG 4  // position-chunks for kv accumulation (1024 positions each)

// K1: qkv = w_qkv(768x256) @ x(b,256,4096) -> bf16
// block 256 = 8 o-threads x 32 p-threads; tile 32 o x 128 p; micro 4o x 4p
__global__ __launch_bounds__(256) void k_qkv(const float* __restrict__ x,
                                             const float* __restrict__ w,
                                             bf16* __restrict__ qkv) {
    int tid = threadIdx.x;
    int to = tid >> 5, tp = tid & 31;
    int pg = blockIdx.x, og = blockIdx.y, b = blockIdx.z;

    __shared__ float sw[256 * 36];  // sw[c*36 + o_local], 36 KB, 16B-aligned rows

    // stage 32x256 weight tile (coalesced read, transposed write)
    for (int i = tid; i < 32 * 256; i += 256) {
        int o = i >> 8, c = i & 255;
        sw[c * 36 + o] = w[(size_t)(og * 32 + o) * 256 + c];
    }
    __syncthreads();

    float acc[4][4];
#pragma unroll
    for (int j = 0; j < 4; ++j)
#pragma unroll
        for (int i = 0; i < 4; ++i) acc[j][i] = 0.f;

    const float* xp = x + (size_t)b * CIN * HW + pg * 128 + tp * 4;
#pragma unroll 4
    for (int c = 0; c < 256; ++c) {
        float4 xv = *(const float4*)(xp + (size_t)c * HW);
        float4 wv = *(const float4*)(&sw[c * 36 + to * 4]);
        acc[0][0] += wv.x * xv.x; acc[0][1] += wv.x * xv.y; acc[0][2] += wv.x * xv.z; acc[0][3] += wv.x * xv.w;
        acc[1][0] += wv.y * xv.x; acc[1][1] += wv.y * xv.y; acc[1][2] += wv.y * xv.z; acc[1][3] += wv.y * xv.w;
        acc[2][0] += wv.z * xv.x; acc[2][1] += wv.z * xv.y; acc[2][2] += wv.z * xv.z; acc[2][3] += wv.z * xv.w;
        acc[3][0] += wv.w * xv.x; acc[3][1] += wv.w * xv.y; acc[3][2] += wv.w * xv.z; acc[3][3] += wv.w * xv.w;
    }

#pragma unroll
    for (int j = 0; j < 4; ++j) {
        int o = og * 32 + to * 4 + j;
        bf16* base = qkv + ((size_t)b * QKV_CH + o) * HW + pg * 128 + tp * 4;
#pragma unroll
        for (int i = 0; i < 4; ++i) base[i] = f2b(acc[j][i]);
    }
}

// K2: depthwise 5x5, pad 2 (cross-correlation), per channel
__global__ void k_dw(const bf16* __restrict__ qkv, const float* __restrict__ wdw,
                     bf16* __restrict__ dw) {
    int p = blockIdx.x * 256 + threadIdx.x;
    int c = blockIdx.y;
    int b = blockIdx.z;
    int y = p >> 6, xc = p & 63;
    const bf16* src = qkv + ((size_t)b * QKV_CH + c) * HW;
    const float* wp = wdw + (size_t)c * 25;
    float acc = 0.f;
#pragma unroll
    for (int ky = 0; ky < 5; ++ky) {
        int yy = y + ky - 2;
        if (yy < 0 || yy > 63) continue;
#pragma unroll
        for (int kx = 0; kx < 5; ++kx) {
            int xx = xc + kx - 2;
            if (xx < 0 || xx > 63) continue;
            acc += wp[ky * 5 + kx] * b2f(src[yy * 64 + xx]);
        }
    }
    dw[((size_t)b * QKV_CH + c) * HW + p] = f2b(acc);
}

// K3: group pointwise 8->8 per group g, IN-PLACE on dw buffer
__global__ void k_agg(bf16* __restrict__ dw, const float* __restrict__ wpw) {
    int p = blockIdx.x * 256 + threadIdx.x;
    int g = blockIdx.y;
    int b = blockIdx.z;
    bf16* base = dw + ((size_t)b * QKV_CH + g * 8) * HW + p;
    float in[8];
#pragma unroll
    for (int i = 0; i < 8; ++i) in[i] = b2f(base[(size_t)i * HW]);
    const float* wp = wpw + (size_t)g * 64;
    float out[8];
#pragma unroll
    for (int o = 0; o < 8; ++o) {
        float acc = 0.f;
#pragma unroll
        for (int i = 0; i < 8; ++i) acc += wp[o * 8 + i] * in[i];
        out[o] = acc;
    }
#pragma unroll
    for (int o = 0; o < 8; ++o) base[(size_t)o * HW] = f2b(out[o]);
}

// K4a: kv partial accumulation. grid (NPG, 64, B), block 256 (4 waves).
// Each thread: 4 consecutive positions, ushort4 loads. Per-wave shfl_xor
// butterfly reduction; one 72-float partial per wave -> part buffer.
// part layout: [(b*64+h)*NPG*4 + pg*4 + wave][72]
__global__ __launch_bounds__(256) void k_kv(const bf16* __restrict__ qkv,
                                            const bf16* __restrict__ agg,
                                            float* __restrict__ part) {
    int tid = threadIdx.x;
    int lane = tid & 63, wv = tid >> 6;
    int pg = blockIdx.x, h = blockIdx.y, b = blockIdx.z;
    int cbase = 24 * h;
    const bf16* src = (h < 32)
        ? qkv + ((size_t)b * QKV_CH + cbase) * HW
        : agg + ((size_t)b * QKV_CH + (cbase - QKV_CH)) * HW;
    int p0 = pg * 1024 + tid * 4;

    float kf[8][4], vf[8][4];
#pragma unroll
    for (int d = 0; d < 8; ++d) {
        ushort4 u = *(const ushort4*)(src + (size_t)(8 + d) * HW + p0);
        kf[d][0] = fmaxf(u2f(u.x), 0.f);
        kf[d][1] = fmaxf(u2f(u.y), 0.f);
        kf[d][2] = fmaxf(u2f(u.z), 0.f);
        kf[d][3] = fmaxf(u2f(u.w), 0.f);
    }
#pragma unroll
    for (int e = 0; e < 8; ++e) {
        ushort4 u = *(const ushort4*)(src + (size_t)(16 + e) * HW + p0);
        vf[e][0] = u2f(u.x); vf[e][1] = u2f(u.y);
        vf[e][2] = u2f(u.z); vf[e][3] = u2f(u.w);
    }

    float acc[72];
#pragma unroll
    for (int i = 0; i < 72; ++i) acc[i] = 0.f;
#pragma unroll
    for (int j = 0; j < 4; ++j) {
#pragma unroll
        for (int d = 0; d < 8; ++d) {
#pragma unroll
            for (int e = 0; e < 8; ++e) acc[d * 9 + e] += kf[d][j] * vf[e][j];
            acc[d * 9 + 8] += kf[d][j];
        }
    }

    // wave-level butterfly: every lane ends with the wave sum of each acc[i]
#pragma unroll
    for (int m = 1; m < 64; m <<= 1) {
#pragma unroll
        for (int i = 0; i < 72; ++i) acc[i] += __shfl_xor(acc[i], m, 64);
    }

    // predicated extract: lane i holds acc[i] (and lanes 0..7 also acc[64+i])
    float t0 = 0.f, t1 = 0.f;
#pragma unroll
    for (int i = 0; i < 64; ++i) t0 = (lane == i) ? acc[i] : t0;
#pragma unroll
    for (int i = 0; i < 8; ++i) t1 = (lane == i) ? acc[64 + i] : t1;

    int bh = b * 64 + h;
    float* pp = part + ((size_t)(bh * NPG + pg) * 4 + wv) * 72;
    pp[lane] = t0;              // lanes 0..63 -> slots 0..63 (coalesced)
    if (lane < 8) pp[64 + lane] = t1;
}

// K4b: apply. grid (4, 64, B). Reduce 16 partials -> skv[72] in LDS,
// then out = q.kv / (q.kv_last + eps), 4 positions/thread, float4 stores.
__global__ __launch_bounds__(256) void k_apply(const bf16* __restrict__ qkv,
                                               const bf16* __restrict__ agg,
                                               const float* __restrict__ part,
                                               float* __restrict__ out) {
    int tid = threadIdx.x;
    int pg = blockIdx.x, h = blockIdx.y, b = blockIdx.z;
    int bh = b * 64 + h;

    __shared__ float skv[72];
    if (tid < 72) {
        const float* pp = part + (size_t)bh * (NPG * 4) * 72 + tid;
        float s = 0.f;
#pragma unroll
        for (int j = 0; j < NPG * 4; ++j) s += pp[(size_t)j * 72];
        skv[tid] = s;
    }
    __syncthreads();

    int cbase = 24 * h;
    const bf16* src = (h < 32)
        ? qkv + ((size_t)b * QKV_CH + cbase) * HW
        : agg + ((size_t)b * QKV_CH + (cbase - QKV_CH)) * HW;
    int p0 = pg * 1024 + tid * 4;

    float qf[8][4];
#pragma unroll
    for (int d = 0; d < 8; ++d) {
        ushort4 u = *(const ushort4*)(src + (size_t)d * HW + p0);
        qf[d][0] = fmaxf(u2f(u.x), 0.f);
        qf[d][1] = fmaxf(u2f(u.y), 0.f);
        qf[d][2] = fmaxf(u2f(u.z), 0.f);
        qf[d][3] = fmaxf(u2f(u.w), 0.f);
    }

    float num[9][4];
#pragma unroll
    for (int e = 0; e < 9; ++e) {
#pragma unroll
        for (int j = 0; j < 4; ++j) {
            float s = 0.f;
#pragma unroll
            for (int d = 0; d < 8; ++d) s += qf[d][j] * skv[d * 9 + e];
            num[e][j] = s;
        }
    }
    float iv[4];
#pragma unroll
    for (int j = 0; j < 4; ++j) iv[j] = 1.f / (num[8][j] + 1e-15f);

#pragma unroll
    for (int e = 0; e < 8; ++e) {
        float4 r;
        r.x = num[e][0] * iv[0];
        r.y = num[e][1] * iv[1];
        r.z = num[e][2] * iv[2];
        r.w = num[e][3] * iv[3];
        *(float4*)(out + ((size_t)b * PROJ_IN + h * 8 + e) * HW + p0) = r;
    }
}

// K5: proj conv1x1 (256x512) + BN affine -> d_out fp32
// block 256 = 8 o x 32 p; tile 32 o x 128 p; c staged in 2 chunks of 256
__global__ __launch_bounds__(256) void k_proj(const float* __restrict__ attn,
                                              const float* __restrict__ w,
                                              const float* __restrict__ gamma,
                                              const float* __restrict__ beta,
                                              const float* __restrict__ mean,
                                              const float* __restrict__ var,
                                              float* __restrict__ out) {
    int tid = threadIdx.x;
    int to = tid >> 5, tp = tid & 31;
    int pg = blockIdx.x, og = blockIdx.y, b = blockIdx.z;

    __shared__ float sw[256 * 36];

    float acc[4][4];
#pragma unroll
    for (int j = 0; j < 4; ++j)
#pragma unroll
        for (int i = 0; i < 4; ++i) acc[j][i] = 0.f;

    const float* ap = attn + (size_t)b * PROJ_IN * HW + pg * 128 + tp * 4;

    for (int h = 0; h < 2; ++h) {
        __syncthreads();
        for (int i = tid; i < 32 * 256; i += 256) {
            int o = i >> 8, c = i & 255;
            sw[c * 36 + o] = w[(size_t)(og * 32 + o) * 512 + h * 256 + c];
        }
        __syncthreads();
#pragma unroll 4
        for (int c = 0; c < 256; ++c) {
            float4 xv = *(const float4*)(ap + (size_t)(h * 256 + c) * HW);
            float4 wv = *(const float4*)(&sw[c * 36 + to * 4]);
            acc[0][0] += wv.x * xv.x; acc[0][1] += wv.x * xv.y; acc[0][2] += wv.x * xv.z; acc[0][3] += wv.x * xv.w;
            acc[1][0] += wv.y * xv.x; acc[1][1] += wv.y * xv.y; acc[1][2] += wv.y * xv.z; acc[1][3] += wv.y * xv.w;
            acc[2][0] += wv.z * xv.x; acc[2][1] += wv.z * xv.y; acc[2][2] += wv.z * xv.z; acc[2][3] += wv.z * xv.w;
            acc[3][0] += wv.w * xv.x; acc[3][1] += wv.w * xv.y; acc[3][2] += wv.w * xv.z; acc[3][3] += wv.w * xv.w;
        }
    }

#pragma unroll
    for (int j = 0; j < 4; ++j) {
        int o = og * 32 + to * 4 + j;
        float inv = gamma[o] * rsqrtf(var[o] + 1e-5f);
        float add = beta[o] - mean[o] * inv;
        float4 r;
        r.x = acc[j][0] * inv + add;
        r.y = acc[j][1] * inv + add;
        r.z = acc[j][2] * inv + add;
        r.w = acc[j][3] * inv + add;
        *(float4*)(out + ((size_t)b * PROJ_OUT + o) * HW + pg * 128 + tp * 4) = r;
    }
}

extern "C" void kernel_launch(void* const* d_in, const int* in_sizes, int n_in,
                              void* d_out, int out_size, void* d_ws, size_t ws_size,
                              hipStream_t stream) {
    const float* x      = (const float*)d_in[0];
    const float* w_qkv  = (const float*)d_in[1];
    const float* w_dw   = (const float*)d_in[2];
    const float* w_pw   = (const float*)d_in[3];
    const float* w_proj = (const float*)d_in[4];
    const float* bn_g   = (const float*)d_in[5];
    const float* bn_b   = (const float*)d_in[6];
    const float* bn_m   = (const float*)d_in[7];
    const float* bn_v   = (const float*)d_in[8];
    float* out = (float*)d_out;

    char* ws = (char*)d_ws;
    bf16*  qkv  = (bf16*)(ws);                           // 8*768*4096*2  = 48 MB
    bf16*  dwb  = (bf16*)(ws + (size_t)50331648);        // 48 MB (dw, then agg in-place)
    float* attn = (float*)(ws + (size_t)100663296);      // 8*512*4096*4  = 64 MB
    // kv partials scratch (2.36 MB): tail of workspace if it fits, else
    // front of d_out (k_proj fully overwrites d_out afterwards, same stream).
    const size_t kMainWs = 167772160;   // 160 MB
    const size_t kPartSz = (size_t)(B * 64) * NPG * 4 * 72 * sizeof(float);
    float* part = (ws_size >= kMainWs + kPartSz) ? (float*)(ws + kMainWs)
                                                 : (float*)d_out;

    dim3 blk(256);
    k_qkv  <<<dim3(32, 24, B), blk, 0, stream>>>(x, w_qkv, qkv);
    k_dw   <<<dim3(16, QKV_CH, B), blk, 0, stream>>>(qkv, w_dw, dwb);
    k_agg  <<<dim3(16, 96, B), blk, 0, stream>>>(dwb, w_pw);
    k_kv   <<<dim3(NPG, 64, B), blk, 0, stream>>>(qkv, dwb, part);
    k_apply<<<dim3(4, 64, B), blk, 0, stream>>>(qkv, dwb, part, attn);
    k_proj <<<dim3(32, 8, B), blk, 0, stream>>>(attn, w_proj, bn_g, bn_b, bn_m, bn_v, out);
}

// Round 3
// 567.862 us; speedup vs baseline: 1.7494x; 1.3787x over previous
//
#include <hip/hip_runtime.h>
#include <hip/hip_bf16.h>

using bf16 = __hip_bfloat16;

__device__ __forceinline__ float b2f(bf16 v) { return __bfloat162float(v); }
__device__ __forceinline__ bf16 f2b(float f) { return __float2bfloat16(f); }
__device__ __forceinline__ float u2f(unsigned short u) {
    return __uint_as_float(((unsigned)u) << 16);
}
// unpack a 32-bit word holding two bf16 (little-endian) to two floats
__device__ __forceinline__ void unpk(unsigned int w, float& a, float& b) {
    a = __uint_as_float(w << 16);
    b = __uint_as_float(w & 0xffff0000u);
}

#define B 8
#define CIN 256
#define HW 4096
#define QKV_CH 768
#define PROJ_IN 512
#define PROJ_OUT 256
#define NPG 4  // position-chunks for kv accumulation (1024 positions each)

// K1: qkv = w_qkv(768x256) @ x(b,256,4096) -> bf16
// block 256 = 8 o-threads x 32 p-threads; tile 32 o x 128 p; micro 4o x 4p
__global__ __launch_bounds__(256) void k_qkv(const float* __restrict__ x,
                                             const float* __restrict__ w,
                                             bf16* __restrict__ qkv) {
    int tid = threadIdx.x;
    int to = tid >> 5, tp = tid & 31;
    int pg = blockIdx.x, og = blockIdx.y, b = blockIdx.z;

    __shared__ float sw[256 * 36];  // sw[c*36 + o_local], 36 KB, 16B-aligned rows

    // stage 32x256 weight tile (coalesced read, transposed write)
    for (int i = tid; i < 32 * 256; i += 256) {
        int o = i >> 8, c = i & 255;
        sw[c * 36 + o] = w[(size_t)(og * 32 + o) * 256 + c];
    }
    __syncthreads();

    float acc[4][4];
#pragma unroll
    for (int j = 0; j < 4; ++j)
#pragma unroll
        for (int i = 0; i < 4; ++i) acc[j][i] = 0.f;

    const float* xp = x + (size_t)b * CIN * HW + pg * 128 + tp * 4;
#pragma unroll 4
    for (int c = 0; c < 256; ++c) {
        float4 xv = *(const float4*)(xp + (size_t)c * HW);
        float4 wv = *(const float4*)(&sw[c * 36 + to * 4]);
        acc[0][0] += wv.x * xv.x; acc[0][1] += wv.x * xv.y; acc[0][2] += wv.x * xv.z; acc[0][3] += wv.x * xv.w;
        acc[1][0] += wv.y * xv.x; acc[1][1] += wv.y * xv.y; acc[1][2] += wv.y * xv.z; acc[1][3] += wv.y * xv.w;
        acc[2][0] += wv.z * xv.x; acc[2][1] += wv.z * xv.y; acc[2][2] += wv.z * xv.z; acc[2][3] += wv.z * xv.w;
        acc[3][0] += wv.w * xv.x; acc[3][1] += wv.w * xv.y; acc[3][2] += wv.w * xv.z; acc[3][3] += wv.w * xv.w;
    }

#pragma unroll
    for (int j = 0; j < 4; ++j) {
        int o = og * 32 + to * 4 + j;
        bf16* base = qkv + ((size_t)b * QKV_CH + o) * HW + pg * 128 + tp * 4;
#pragma unroll
        for (int i = 0; i < 4; ++i) base[i] = f2b(acc[j][i]);
    }
}

// K2+K3 fused: depthwise 5x5 (pad 2, cross-corr) + group 8->8 pointwise mix.
// grid (2, 96, B), block 256 = 8 x-threads (8 px each) x 32 rows.
// Per thread: 8 px x 1 row; loop 8 in-channels; dw in registers (vector
// loads, 16 bf16 window per row); mix into acc[oc][px]; one uint4 store/oc.
__global__ __launch_bounds__(256) void k_dwagg(const bf16* __restrict__ qkv,
                                               const float* __restrict__ wdw,
                                               const float* __restrict__ wpw,
                                               bf16* __restrict__ dw) {
    int tid = threadIdx.x;
    int g = blockIdx.y, b = blockIdx.z;
    int x0 = (tid & 7) * 8;
    int y  = blockIdx.x * 32 + (tid >> 3);

    __shared__ float sdw[200];  // 8 ch x 25
    __shared__ float spw[64];   // 8 oc x 8 ic
    if (tid < 200) sdw[tid] = wdw[(size_t)g * 200 + tid];
    if (tid < 64)  spw[tid] = wpw[(size_t)g * 64 + tid];
    __syncthreads();

    const bf16* src0 = qkv + ((size_t)b * QKV_CH + g * 8) * HW;

    float acc[8][8];
#pragma unroll
    for (int oc = 0; oc < 8; ++oc)
#pragma unroll
        for (int px = 0; px < 8; ++px) acc[oc][px] = 0.f;

#pragma unroll
    for (int c = 0; c < 8; ++c) {
        const bf16* src = src0 + (size_t)c * HW;
        float d[8];
#pragma unroll
        for (int px = 0; px < 8; ++px) d[px] = 0.f;

#pragma unroll
        for (int ky = 0; ky < 5; ++ky) {
            int yy = y + ky - 2;
            if (yy < 0 || yy > 63) continue;
            const bf16* row = src + yy * 64;
            float f[16];  // covers global x: x0-4 .. x0+11
            if (x0 > 0) {
                uint2 u = *(const uint2*)(row + x0 - 4);
                unpk(u.x, f[0], f[1]); unpk(u.y, f[2], f[3]);
            } else {
                f[0] = f[1] = f[2] = f[3] = 0.f;
            }
            uint4 m = *(const uint4*)(row + x0);
            unpk(m.x, f[4], f[5]);  unpk(m.y, f[6], f[7]);
            unpk(m.z, f[8], f[9]);  unpk(m.w, f[10], f[11]);
            if (x0 < 56) {
                uint2 u = *(const uint2*)(row + x0 + 8);
                unpk(u.x, f[12], f[13]); unpk(u.y, f[14], f[15]);
            } else {
                f[12] = f[13] = f[14] = f[15] = 0.f;
            }
#pragma unroll
            for (int kx = 0; kx < 5; ++kx) {
                float wv = sdw[c * 25 + ky * 5 + kx];
#pragma unroll
                for (int px = 0; px < 8; ++px) d[px] += wv * f[px + kx + 2];
            }
        }
        // pointwise mix: acc[oc] += wpw[g][oc][c] * d  (fp32, pre-rounding)
#pragma unroll
        for (int oc = 0; oc < 8; ++oc) {
            float wm = spw[oc * 8 + c];
#pragma unroll
            for (int px = 0; px < 8; ++px) acc[oc][px] += wm * d[px];
        }
    }

#pragma unroll
    for (int oc = 0; oc < 8; ++oc) {
        union { bf16 h[8]; uint4 v; } pk;
#pragma unroll
        for (int px = 0; px < 8; ++px) pk.h[px] = f2b(acc[oc][px]);
        *(uint4*)(dw + ((size_t)b * QKV_CH + g * 8 + oc) * HW + y * 64 + x0) = pk.v;
    }
}

// K4a: kv partial accumulation. grid (NPG, 64, B), block 256 (4 waves).
// Each thread: 4 consecutive positions, ushort4 loads. Per-wave shfl_xor
// butterfly reduction; one 72-float partial per wave -> part buffer.
// part layout: [(b*64+h)*NPG*4 + pg*4 + wave][72]
__global__ __launch_bounds__(256) void k_kv(const bf16* __restrict__ qkv,
                                            const bf16* __restrict__ agg,
                                            float* __restrict__ part) {
    int tid = threadIdx.x;
    int lane = tid & 63, wv = tid >> 6;
    int pg = blockIdx.x, h = blockIdx.y, b = blockIdx.z;
    int cbase = 24 * h;
    const bf16* src = (h < 32)
        ? qkv + ((size_t)b * QKV_CH + cbase) * HW
        : agg + ((size_t)b * QKV_CH + (cbase - QKV_CH)) * HW;
    int p0 = pg * 1024 + tid * 4;

    float kf[8][4], vf[8][4];
#pragma unroll
    for (int d = 0; d < 8; ++d) {
        ushort4 u = *(const ushort4*)(src + (size_t)(8 + d) * HW + p0);
        kf[d][0] = fmaxf(u2f(u.x), 0.f);
        kf[d][1] = fmaxf(u2f(u.y), 0.f);
        kf[d][2] = fmaxf(u2f(u.z), 0.f);
        kf[d][3] = fmaxf(u2f(u.w), 0.f);
    }
#pragma unroll
    for (int e = 0; e < 8; ++e) {
        ushort4 u = *(const ushort4*)(src + (size_t)(16 + e) * HW + p0);
        vf[e][0] = u2f(u.x); vf[e][1] = u2f(u.y);
        vf[e][2] = u2f(u.z); vf[e][3] = u2f(u.w);
    }

    float acc[72];
#pragma unroll
    for (int i = 0; i < 72; ++i) acc[i] = 0.f;
#pragma unroll
    for (int j = 0; j < 4; ++j) {
#pragma unroll
        for (int d = 0; d < 8; ++d) {
#pragma unroll
            for (int e = 0; e < 8; ++e) acc[d * 9 + e] += kf[d][j] * vf[e][j];
            acc[d * 9 + 8] += kf[d][j];
        }
    }

    // wave-level butterfly: every lane ends with the wave sum of each acc[i]
#pragma unroll
    for (int m = 1; m < 64; m <<= 1) {
#pragma unroll
        for (int i = 0; i < 72; ++i) acc[i] += __shfl_xor(acc[i], m, 64);
    }

    // predicated extract: lane i holds acc[i] (and lanes 0..7 also acc[64+i])
    float t0 = 0.f, t1 = 0.f;
#pragma unroll
    for (int i = 0; i < 64; ++i) t0 = (lane == i) ? acc[i] : t0;
#pragma unroll
    for (int i = 0; i < 8; ++i) t1 = (lane == i) ? acc[64 + i] : t1;

    int bh = b * 64 + h;
    float* pp = part + ((size_t)(bh * NPG + pg) * 4 + wv) * 72;
    pp[lane] = t0;              // lanes 0..63 -> slots 0..63 (coalesced)
    if (lane < 8) pp[64 + lane] = t1;
}

// K4b: apply. grid (4, 64, B). Reduce 16 partials -> skv[72] in LDS,
// then out = q.kv / (q.kv_last + eps), 4 positions/thread, float4 stores.
__global__ __launch_bounds__(256) void k_apply(const bf16* __restrict__ qkv,
                                               const bf16* __restrict__ agg,
                                               const float* __restrict__ part,
                                               float* __restrict__ out) {
    int tid = threadIdx.x;
    int pg = blockIdx.x, h = blockIdx.y, b = blockIdx.z;
    int bh = b * 64 + h;

    __shared__ float skv[72];
    if (tid < 72) {
        const float* pp = part + (size_t)bh * (NPG * 4) * 72 + tid;
        float s = 0.f;
#pragma unroll
        for (int j = 0; j < NPG * 4; ++j) s += pp[(size_t)j * 72];
        skv[tid] = s;
    }
    __syncthreads();

    int cbase = 24 * h;
    const bf16* src = (h < 32)
        ? qkv + ((size_t)b * QKV_CH + cbase) * HW
        : agg + ((size_t)b * QKV_CH + (cbase - QKV_CH)) * HW;
    int p0 = pg * 1024 + tid * 4;

    float qf[8][4];
#pragma unroll
    for (int d = 0; d < 8; ++d) {
        ushort4 u = *(const ushort4*)(src + (size_t)d * HW + p0);
        qf[d][0] = fmaxf(u2f(u.x), 0.f);
        qf[d][1] = fmaxf(u2f(u.y), 0.f);
        qf[d][2] = fmaxf(u2f(u.z), 0.f);
        qf[d][3] = fmaxf(u2f(u.w), 0.f);
    }

    float num[9][4];
#pragma unroll
    for (int e = 0; e < 9; ++e) {
#pragma unroll
        for (int j = 0; j < 4; ++j) {
            float s = 0.f;
#pragma unroll
            for (int d = 0; d < 8; ++d) s += qf[d][j] * skv[d * 9 + e];
            num[e][j] = s;
        }
    }
    float iv[4];
#pragma unroll
    for (int j = 0; j < 4; ++j) iv[j] = 1.f / (num[8][j] + 1e-15f);

#pragma unroll
    for (int e = 0; e < 8; ++e) {
        float4 r;
        r.x = num[e][0] * iv[0];
        r.y = num[e][1] * iv[1];
        r.z = num[e][2] * iv[2];
        r.w = num[e][3] * iv[3];
        *(float4*)(out + ((size_t)b * PROJ_IN + h * 8 + e) * HW + p0) = r;
    }
}

// K5: proj conv1x1 (256x512) + BN affine -> d_out fp32
// block 256 = 8 o x 32 p; tile 32 o x 128 p; c staged in 2 chunks of 256
__global__ __launch_bounds__(256) void k_proj(const float* __restrict__ attn,
                                              const float* __restrict__ w,
                                              const float* __restrict__ gamma,
                                              const float* __restrict__ beta,
                                              const float* __restrict__ mean,
                                              const float* __restrict__ var,
                                              float* __restrict__ out) {
    int tid = threadIdx.x;
    int to = tid >> 5, tp = tid & 31;
    int pg = blockIdx.x, og = blockIdx.y, b = blockIdx.z;

    __shared__ float sw[256 * 36];

    float acc[4][4];
#pragma unroll
    for (int j = 0; j < 4; ++j)
#pragma unroll
        for (int i = 0; i < 4; ++i) acc[j][i] = 0.f;

    const float* ap = attn + (size_t)b * PROJ_IN * HW + pg * 128 + tp * 4;

    for (int h = 0; h < 2; ++h) {
        __syncthreads();
        for (int i = tid; i < 32 * 256; i += 256) {
            int o = i >> 8, c = i & 255;
            sw[c * 36 + o] = w[(size_t)(og * 32 + o) * 512 + h * 256 + c];
        }
        __syncthreads();
#pragma unroll 4
        for (int c = 0; c < 256; ++c) {
            float4 xv = *(const float4*)(ap + (size_t)(h * 256 + c) * HW);
            float4 wv = *(const float4*)(&sw[c * 36 + to * 4]);
            acc[0][0] += wv.x * xv.x; acc[0][1] += wv.x * xv.y; acc[0][2] += wv.x * xv.z; acc[0][3] += wv.x * xv.w;
            acc[1][0] += wv.y * xv.x; acc[1][1] += wv.y * xv.y; acc[1][2] += wv.y * xv.z; acc[1][3] += wv.y * xv.w;
            acc[2][0] += wv.z * xv.x; acc[2][1] += wv.z * xv.y; acc[2][2] += wv.z * xv.z; acc[2][3] += wv.z * xv.w;
            acc[3][0] += wv.w * xv.x; acc[3][1] += wv.w * xv.y; acc[3][2] += wv.w * xv.z; acc[3][3] += wv.w * xv.w;
        }
    }

#pragma unroll
    for (int j = 0; j < 4; ++j) {
        int o = og * 32 + to * 4 + j;
        float inv = gamma[o] * rsqrtf(var[o] + 1e-5f);
        float add = beta[o] - mean[o] * inv;
        float4 r;
        r.x = acc[j][0] * inv + add;
        r.y = acc[j][1] * inv + add;
        r.z = acc[j][2] * inv + add;
        r.w = acc[j][3] * inv + add;
        *(float4*)(out + ((size_t)b * PROJ_OUT + o) * HW + pg * 128 + tp * 4) = r;
    }
}

extern "C" void kernel_launch(void* const* d_in, const int* in_sizes, int n_in,
                              void* d_out, int out_size, void* d_ws, size_t ws_size,
                              hipStream_t stream) {
    const float* x      = (const float*)d_in[0];
    const float* w_qkv  = (const float*)d_in[1];
    const float* w_dw   = (const float*)d_in[2];
    const float* w_pw   = (const float*)d_in[3];
    const float* w_proj = (const float*)d_in[4];
    const float* bn_g   = (const float*)d_in[5];
    const float* bn_b   = (const float*)d_in[6];
    const float* bn_m   = (const float*)d_in[7];
    const float* bn_v   = (const float*)d_in[8];
    float* out = (float*)d_out;

    char* ws = (char*)d_ws;
    bf16*  qkv  = (bf16*)(ws);                           // 8*768*4096*2  = 48 MB
    bf16*  dwb  = (bf16*)(ws + (size_t)50331648);        // 48 MB (fused dw+agg result)
    float* attn = (float*)(ws + (size_t)100663296);      // 8*512*4096*4  = 64 MB
    // kv partials scratch (2.36 MB): tail of workspace if it fits, else
    // front of d_out (k_proj fully overwrites d_out afterwards, same stream).
    const size_t kMainWs = 167772160;   // 160 MB
    const size_t kPartSz = (size_t)(B * 64) * NPG * 4 * 72 * sizeof(float);
    float* part = (ws_size >= kMainWs + kPartSz) ? (float*)(ws + kMainWs)
                                                 : (float*)d_out;

    dim3 blk(256);
    k_qkv  <<<dim3(32, 24, B), blk, 0, stream>>>(x, w_qkv, qkv);
    k_dwagg<<<dim3(2, 96, B), blk, 0, stream>>>(qkv, w_dw, w_pw, dwb);
    k_kv   <<<dim3(NPG, 64, B), blk, 0, stream>>>(qkv, dwb, part);
    k_apply<<<dim3(4, 64, B), blk, 0, stream>>>(qkv, dwb, part, attn);
    k_proj <<<dim3(32, 8, B), blk, 0, stream>>>(attn, w_proj, bn_g, bn_b, bn_m, bn_v, out);
}

// Round 9
// 558.783 us; speedup vs baseline: 1.7778x; 1.0162x over previous
//
#include <hip/hip_runtime.h>
#include <hip/hip_bf16.h>

using bf16 = __hip_bfloat16;

__device__ __forceinline__ float b2f(bf16 v) { return __bfloat162float(v); }
__device__ __forceinline__ bf16 f2b(float f) { return __float2bfloat16(f); }
__device__ __forceinline__ float u2f(unsigned short u) {
    return __uint_as_float(((unsigned)u) << 16);
}
// unpack a 32-bit word holding two bf16 (little-endian) to two floats
__device__ __forceinline__ void unpk(unsigned int w, float& a, float& b) {
    a = __uint_as_float(w << 16);
    b = __uint_as_float(w & 0xffff0000u);
}

#define B 8
#define CIN 256
#define HW 4096
#define QKV_CH 768
#define PROJ_IN 512
#define PROJ_OUT 256
#define NPG 4

// K1: qkv = w_qkv(768x256) @ x(b,256,4096) -> bf16
// block 256 = 8 o-threads x 32 p-threads; tile 32 o x 256 p; micro 4o x 8p
// (VALU fp32; 32 FMA per c-iter per thread -> halves per-FMA overhead vs 4x4)
__global__ __launch_bounds__(256) void k_qkv(const float* __restrict__ x,
                                             const float* __restrict__ w,
                                             bf16* __restrict__ qkv) {
    int tid = threadIdx.x;
    int to = tid >> 5, tp = tid & 31;
    int pg = blockIdx.x, og = blockIdx.y, b = blockIdx.z;

    __shared__ float sw[256 * 36];  // sw[c*36 + o_local], 36 KB

    for (int i = tid; i < 32 * 256; i += 256) {
        int o = i >> 8, c = i & 255;
        sw[c * 36 + o] = w[(size_t)(og * 32 + o) * 256 + c];
    }
    __syncthreads();

    float acc[4][8];
#pragma unroll
    for (int j = 0; j < 4; ++j)
#pragma unroll
        for (int i = 0; i < 8; ++i) acc[j][i] = 0.f;

    const float* xp = x + (size_t)b * CIN * HW + pg * 256 + tp * 8;
#pragma unroll 4
    for (int c = 0; c < 256; ++c) {
        float4 x0 = *(const float4*)(xp + (size_t)c * HW);
        float4 x1 = *(const float4*)(xp + (size_t)c * HW + 4);
        float4 wv = *(const float4*)(&sw[c * 36 + to * 4]);
        float xs[8] = {x0.x, x0.y, x0.z, x0.w, x1.x, x1.y, x1.z, x1.w};
        float ws[4] = {wv.x, wv.y, wv.z, wv.w};
#pragma unroll
        for (int j = 0; j < 4; ++j)
#pragma unroll
            for (int i = 0; i < 8; ++i) acc[j][i] += ws[j] * xs[i];
    }

#pragma unroll
    for (int j = 0; j < 4; ++j) {
        int o = og * 32 + to * 4 + j;
        union { bf16 h[8]; uint4 v; } pk;
#pragma unroll
        for (int i = 0; i < 8; ++i) pk.h[i] = f2b(acc[j][i]);
        *(uint4*)(qkv + ((size_t)b * QKV_CH + o) * HW + pg * 256 + tp * 8) = pk.v;
    }
}

// K2+K3 fused: depthwise 5x5 (pad 2) + group 8->8 pointwise mix. grid (2, 96, B)
__global__ __launch_bounds__(256) void k_dwagg(const bf16* __restrict__ qkv,
                                               const float* __restrict__ wdw,
                                               const float* __restrict__ wpw,
                                               bf16* __restrict__ dw) {
    int tid = threadIdx.x;
    int g = blockIdx.y, b = blockIdx.z;
    int x0 = (tid & 7) * 8;
    int y  = blockIdx.x * 32 + (tid >> 3);

    __shared__ float sdw[200];
    __shared__ float spw[64];
    if (tid < 200) sdw[tid] = wdw[(size_t)g * 200 + tid];
    if (tid < 64)  spw[tid] = wpw[(size_t)g * 64 + tid];
    __syncthreads();

    const bf16* src0 = qkv + ((size_t)b * QKV_CH + g * 8) * HW;

    float acc[8][8];
#pragma unroll
    for (int oc = 0; oc < 8; ++oc)
#pragma unroll
        for (int px = 0; px < 8; ++px) acc[oc][px] = 0.f;

#pragma unroll
    for (int c = 0; c < 8; ++c) {
        const bf16* src = src0 + (size_t)c * HW;
        float d[8];
#pragma unroll
        for (int px = 0; px < 8; ++px) d[px] = 0.f;

#pragma unroll
        for (int ky = 0; ky < 5; ++ky) {
            int yy = y + ky - 2;
            if (yy < 0 || yy > 63) continue;
            const bf16* row = src + yy * 64;
            float f[16];
            if (x0 > 0) {
                uint2 u = *(const uint2*)(row + x0 - 4);
                unpk(u.x, f[0], f[1]); unpk(u.y, f[2], f[3]);
            } else {
                f[0] = f[1] = f[2] = f[3] = 0.f;
            }
            uint4 m = *(const uint4*)(row + x0);
            unpk(m.x, f[4], f[5]);  unpk(m.y, f[6], f[7]);
            unpk(m.z, f[8], f[9]);  unpk(m.w, f[10], f[11]);
            if (x0 < 56) {
                uint2 u = *(const uint2*)(row + x0 + 8);
                unpk(u.x, f[12], f[13]); unpk(u.y, f[14], f[15]);
            } else {
                f[12] = f[13] = f[14] = f[15] = 0.f;
            }
#pragma unroll
            for (int kx = 0; kx < 5; ++kx) {
                float wv = sdw[c * 25 + ky * 5 + kx];
#pragma unroll
                for (int px = 0; px < 8; ++px) d[px] += wv * f[px + kx + 2];
            }
        }
#pragma unroll
        for (int oc = 0; oc < 8; ++oc) {
            float wm = spw[oc * 8 + c];
#pragma unroll
            for (int px = 0; px < 8; ++px) acc[oc][px] += wm * d[px];
        }
    }

#pragma unroll
    for (int oc = 0; oc < 8; ++oc) {
        union { bf16 h[8]; uint4 v; } pk;
#pragma unroll
        for (int px = 0; px < 8; ++px) pk.h[px] = f2b(acc[oc][px]);
        *(uint4*)(dw + ((size_t)b * QKV_CH + g * 8 + oc) * HW + y * 64 + x0) = pk.v;
    }
}

// K4a: kv partial accumulation. grid (NPG, 64, B)
__global__ __launch_bounds__(256) void k_kv(const bf16* __restrict__ qkv,
                                            const bf16* __restrict__ agg,
                                            float* __restrict__ part) {
    int tid = threadIdx.x;
    int lane = tid & 63, wv = tid >> 6;
    int pg = blockIdx.x, h = blockIdx.y, b = blockIdx.z;
    int cbase = 24 * h;
    const bf16* src = (h < 32)
        ? qkv + ((size_t)b * QKV_CH + cbase) * HW
        : agg + ((size_t)b * QKV_CH + (cbase - QKV_CH)) * HW;
    int p0 = pg * 1024 + tid * 4;

    float kf[8][4], vf[8][4];
#pragma unroll
    for (int d = 0; d < 8; ++d) {
        ushort4 u = *(const ushort4*)(src + (size_t)(8 + d) * HW + p0);
        kf[d][0] = fmaxf(u2f(u.x), 0.f);
        kf[d][1] = fmaxf(u2f(u.y), 0.f);
        kf[d][2] = fmaxf(u2f(u.z), 0.f);
        kf[d][3] = fmaxf(u2f(u.w), 0.f);
    }
#pragma unroll
    for (int e = 0; e < 8; ++e) {
        ushort4 u = *(const ushort4*)(src + (size_t)(16 + e) * HW + p0);
        vf[e][0] = u2f(u.x); vf[e][1] = u2f(u.y);
        vf[e][2] = u2f(u.z); vf[e][3] = u2f(u.w);
    }

    float acc[72];
#pragma unroll
    for (int i = 0; i < 72; ++i) acc[i] = 0.f;
#pragma unroll
    for (int j = 0; j < 4; ++j) {
#pragma unroll
        for (int d = 0; d < 8; ++d) {
#pragma unroll
            for (int e = 0; e < 8; ++e) acc[d * 9 + e] += kf[d][j] * vf[e][j];
            acc[d * 9 + 8] += kf[d][j];
        }
    }

#pragma unroll
    for (int m = 1; m < 64; m <<= 1) {
#pragma unroll
        for (int i = 0; i < 72; ++i) acc[i] += __shfl_xor(acc[i], m, 64);
    }

    float t0 = 0.f, t1 = 0.f;
#pragma unroll
    for (int i = 0; i < 64; ++i) t0 = (lane == i) ? acc[i] : t0;
#pragma unroll
    for (int i = 0; i < 8; ++i) t1 = (lane == i) ? acc[64 + i] : t1;

    int bh = b * 64 + h;
    float* pp = part + ((size_t)(bh * NPG + pg) * 4 + wv) * 72;
    pp[lane] = t0;
    if (lane < 8) pp[64 + lane] = t1;
}

// K4b: apply. grid (4, 64, B)
__global__ __launch_bounds__(256) void k_apply(const bf16* __restrict__ qkv,
                                               const bf16* __restrict__ agg,
                                               const float* __restrict__ part,
                                               float* __restrict__ out) {
    int tid = threadIdx.x;
    int pg = blockIdx.x, h = blockIdx.y, b = blockIdx.z;
    int bh = b * 64 + h;

    __shared__ float skv[72];
    if (tid < 72) {
        const float* pp = part + (size_t)bh * (NPG * 4) * 72 + tid;
        float s = 0.f;
#pragma unroll
        for (int j = 0; j < NPG * 4; ++j) s += pp[(size_t)j * 72];
        skv[tid] = s;
    }
    __syncthreads();

    int cbase = 24 * h;
    const bf16* src = (h < 32)
        ? qkv + ((size_t)b * QKV_CH + cbase) * HW
        : agg + ((size_t)b * QKV_CH + (cbase - QKV_CH)) * HW;
    int p0 = pg * 1024 + tid * 4;

    float qf[8][4];
#pragma unroll
    for (int d = 0; d < 8; ++d) {
        ushort4 u = *(const ushort4*)(src + (size_t)d * HW + p0);
        qf[d][0] = fmaxf(u2f(u.x), 0.f);
        qf[d][1] = fmaxf(u2f(u.y), 0.f);
        qf[d][2] = fmaxf(u2f(u.z), 0.f);
        qf[d][3] = fmaxf(u2f(u.w), 0.f);
    }

    float num[9][4];
#pragma unroll
    for (int e = 0; e < 9; ++e) {
#pragma unroll
        for (int j = 0; j < 4; ++j) {
            float s = 0.f;
#pragma unroll
            for (int d = 0; d < 8; ++d) s += qf[d][j] * skv[d * 9 + e];
            num[e][j] = s;
        }
    }
    float iv[4];
#pragma unroll
    for (int j = 0; j < 4; ++j) iv[j] = 1.f / (num[8][j] + 1e-15f);

#pragma unroll
    for (int e = 0; e < 8; ++e) {
        float4 r;
        r.x = num[e][0] * iv[0];
        r.y = num[e][1] * iv[1];
        r.z = num[e][2] * iv[2];
        r.w = num[e][3] * iv[3];
        *(float4*)(out + ((size_t)b * PROJ_IN + h * 8 + e) * HW + p0) = r;
    }
}

// K5: proj conv1x1 (256x512) + BN affine -> d_out fp32
// block 256 = 8 o x 32 p; tile 32 o x 256 p; micro 4o x 8p; c in 2 chunks
__global__ __launch_bounds__(256) void k_proj(const float* __restrict__ attn,
                                              const float* __restrict__ w,
                                              const float* __restrict__ gamma,
                                              const float* __restrict__ beta,
                                              const float* __restrict__ mean,
                                              const float* __restrict__ var,
                                              float* __restrict__ out) {
    int tid = threadIdx.x;
    int to = tid >> 5, tp = tid & 31;
    int pg = blockIdx.x, og = blockIdx.y, b = blockIdx.z;

    __shared__ float sw[256 * 36];

    float acc[4][8];
#pragma unroll
    for (int j = 0; j < 4; ++j)
#pragma unroll
        for (int i = 0; i < 8; ++i) acc[j][i] = 0.f;

    const float* ap = attn + (size_t)b * PROJ_IN * HW + pg * 256 + tp * 8;

    for (int h = 0; h < 2; ++h) {
        __syncthreads();
        for (int i = tid; i < 32 * 256; i += 256) {
            int o = i >> 8, c = i & 255;
            sw[c * 36 + o] = w[(size_t)(og * 32 + o) * 512 + h * 256 + c];
        }
        __syncthreads();
#pragma unroll 4
        for (int c = 0; c < 256; ++c) {
            float4 x0 = *(const float4*)(ap + (size_t)(h * 256 + c) * HW);
            float4 x1 = *(const float4*)(ap + (size_t)(h * 256 + c) * HW + 4);
            float4 wv = *(const float4*)(&sw[c * 36 + to * 4]);
            float xs[8] = {x0.x, x0.y, x0.z, x0.w, x1.x, x1.y, x1.z, x1.w};
            float ws[4] = {wv.x, wv.y, wv.z, wv.w};
#pragma unroll
            for (int j = 0; j < 4; ++j)
#pragma unroll
                for (int i = 0; i < 8; ++i) acc[j][i] += ws[j] * xs[i];
        }
    }

#pragma unroll
    for (int j = 0; j < 4; ++j) {
        int o = og * 32 + to * 4 + j;
        float inv = gamma[o] * rsqrtf(var[o] + 1e-5f);
        float add = beta[o] - mean[o] * inv;
        float* ob = out + ((size_t)b * PROJ_OUT + o) * HW + pg * 256 + tp * 8;
        float4 r0, r1;
        r0.x = acc[j][0] * inv + add; r0.y = acc[j][1] * inv + add;
        r0.z = acc[j][2] * inv + add; r0.w = acc[j][3] * inv + add;
        r1.x = acc[j][4] * inv + add; r1.y = acc[j][5] * inv + add;
        r1.z = acc[j][6] * inv + add; r1.w = acc[j][7] * inv + add;
        *(float4*)ob = r0;
        *(float4*)(ob + 4) = r1;
    }
}

extern "C" void kernel_launch(void* const* d_in, const int* in_sizes, int n_in,
                              void* d_out, int out_size, void* d_ws, size_t ws_size,
                              hipStream_t stream) {
    const float* x      = (const float*)d_in[0];
    const float* w_qkv  = (const float*)d_in[1];
    const float* w_dw   = (const float*)d_in[2];
    const float* w_pw   = (const float*)d_in[3];
    const float* w_proj = (const float*)d_in[4];
    const float* bn_g   = (const float*)d_in[5];
    const float* bn_b   = (const float*)d_in[6];
    const float* bn_m   = (const float*)d_in[7];
    const float* bn_v   = (const float*)d_in[8];
    float* out = (float*)d_out;

    char* ws = (char*)d_ws;
    bf16*  qkv  = (bf16*)(ws);                           // 48 MB
    bf16*  dwb  = (bf16*)(ws + (size_t)50331648);        // 48 MB
    float* attn = (float*)(ws + (size_t)100663296);      // 64 MB
    const size_t kMainWs = 167772160;                    // 160 MB
    const size_t kPartSz = (size_t)(B * 64) * NPG * 4 * 72 * sizeof(float);
    float* part = (ws_size >= kMainWs + kPartSz) ? (float*)(ws + kMainWs)
                                                 : (float*)d_out;

    dim3 blk(256);
    k_qkv  <<<dim3(16, 24, B), blk, 0, stream>>>(x, w_qkv, qkv);
    k_dwagg<<<dim3(2, 96, B), blk, 0, stream>>>(qkv, w_dw, w_pw, dwb);
    k_kv   <<<dim3(NPG, 64, B), blk, 0, stream>>>(qkv, dwb, part);
    k_apply<<<dim3(4, 64, B), blk, 0, stream>>>(qkv, dwb, part, attn);
    k_proj <<<dim3(16, 8, B), blk, 0, stream>>>(attn, w_proj, bn_g, bn_b, bn_m, bn_v, out);
}

// Round 10
// 537.918 us; speedup vs baseline: 1.8467x; 1.0388x over previous
//
#include <hip/hip_runtime.h>
#include <hip/hip_bf16.h>

using bf16 = __hip_bfloat16;

__device__ __forceinline__ float b2f(bf16 v) { return __bfloat162float(v); }
__device__ __forceinline__ bf16 f2b(float f) { return __float2bfloat16(f); }
__device__ __forceinline__ float u2f(unsigned short u) {
    return __uint_as_float(((unsigned)u) << 16);
}
// unpack a 32-bit word holding two bf16 (little-endian) to two floats
__device__ __forceinline__ void unpk(unsigned int w, float& a, float& b) {
    a = __uint_as_float(w << 16);
    b = __uint_as_float(w & 0xffff0000u);
}

#define B 8
#define CIN 256
#define HW 4096
#define QKV_CH 768
#define PROJ_IN 512
#define PROJ_OUT 256
#define NPG 4

// K1: qkv = w_qkv(768x256) @ x(b,256,4096) -> bf16
// block 256 = 2 o-groups x 128 p-threads; tile 32 o x 512 p; micro 16o x 4p.
// Each thread: 1 global float4 (x) + 4 LDS float4 (w, wave-broadcast) +
// 64 FMA per c-iter. x L1 traffic scales as 768/MO: MO=4 was 6.1 GB/dispatch
// (L1-return-BW bound, ~155us floor); MO=16 -> 1.5 GB (~38us, below FMA floor).
__global__ __launch_bounds__(256) void k_qkv(const float* __restrict__ x,
                                             const float* __restrict__ w,
                                             bf16* __restrict__ qkv) {
    int tid = threadIdx.x;
    int to = tid >> 7, tp = tid & 127;
    int pg = blockIdx.x, og = blockIdx.y, b = blockIdx.z;

    __shared__ float sw[256 * 36];  // sw[c*36 + o_local], 36 KB

    for (int i = tid; i < 32 * 256; i += 256) {
        int o = i >> 8, c = i & 255;
        sw[c * 36 + o] = w[(size_t)(og * 32 + o) * 256 + c];
    }
    __syncthreads();

    float acc[16][4];
#pragma unroll
    for (int j = 0; j < 16; ++j)
#pragma unroll
        for (int i = 0; i < 4; ++i) acc[j][i] = 0.f;

    const float* xp = x + (size_t)b * CIN * HW + pg * 512 + tp * 4;
#pragma unroll 4
    for (int c = 0; c < 256; ++c) {
        float4 xv = *(const float4*)(xp + (size_t)c * HW);
        const float* wr = &sw[c * 36 + to * 16];
        float4 w0 = *(const float4*)(wr);
        float4 w1 = *(const float4*)(wr + 4);
        float4 w2 = *(const float4*)(wr + 8);
        float4 w3 = *(const float4*)(wr + 12);
        float xs[4] = {xv.x, xv.y, xv.z, xv.w};
        float ws[16] = {w0.x, w0.y, w0.z, w0.w, w1.x, w1.y, w1.z, w1.w,
                        w2.x, w2.y, w2.z, w2.w, w3.x, w3.y, w3.z, w3.w};
#pragma unroll
        for (int j = 0; j < 16; ++j)
#pragma unroll
            for (int i = 0; i < 4; ++i) acc[j][i] += ws[j] * xs[i];
    }

#pragma unroll
    for (int j = 0; j < 16; ++j) {
        int o = og * 32 + to * 16 + j;
        union { bf16 h[4]; uint2 v; } pk;
#pragma unroll
        for (int i = 0; i < 4; ++i) pk.h[i] = f2b(acc[j][i]);
        *(uint2*)(qkv + ((size_t)b * QKV_CH + o) * HW + pg * 512 + tp * 4) = pk.v;
    }
}

// K2+K3 fused: depthwise 5x5 (pad 2) + group 8->8 pointwise mix. grid (2, 96, B)
__global__ __launch_bounds__(256) void k_dwagg(const bf16* __restrict__ qkv,
                                               const float* __restrict__ wdw,
                                               const float* __restrict__ wpw,
                                               bf16* __restrict__ dw) {
    int tid = threadIdx.x;
    int g = blockIdx.y, b = blockIdx.z;
    int x0 = (tid & 7) * 8;
    int y  = blockIdx.x * 32 + (tid >> 3);

    __shared__ float sdw[200];
    __shared__ float spw[64];
    if (tid < 200) sdw[tid] = wdw[(size_t)g * 200 + tid];
    if (tid < 64)  spw[tid] = wpw[(size_t)g * 64 + tid];
    __syncthreads();

    const bf16* src0 = qkv + ((size_t)b * QKV_CH + g * 8) * HW;

    float acc[8][8];
#pragma unroll
    for (int oc = 0; oc < 8; ++oc)
#pragma unroll
        for (int px = 0; px < 8; ++px) acc[oc][px] = 0.f;

#pragma unroll
    for (int c = 0; c < 8; ++c) {
        const bf16* src = src0 + (size_t)c * HW;
        float d[8];
#pragma unroll
        for (int px = 0; px < 8; ++px) d[px] = 0.f;

#pragma unroll
        for (int ky = 0; ky < 5; ++ky) {
            int yy = y + ky - 2;
            if (yy < 0 || yy > 63) continue;
            const bf16* row = src + yy * 64;
            float f[16];
            if (x0 > 0) {
                uint2 u = *(const uint2*)(row + x0 - 4);
                unpk(u.x, f[0], f[1]); unpk(u.y, f[2], f[3]);
            } else {
                f[0] = f[1] = f[2] = f[3] = 0.f;
            }
            uint4 m = *(const uint4*)(row + x0);
            unpk(m.x, f[4], f[5]);  unpk(m.y, f[6], f[7]);
            unpk(m.z, f[8], f[9]);  unpk(m.w, f[10], f[11]);
            if (x0 < 56) {
                uint2 u = *(const uint2*)(row + x0 + 8);
                unpk(u.x, f[12], f[13]); unpk(u.y, f[14], f[15]);
            } else {
                f[12] = f[13] = f[14] = f[15] = 0.f;
            }
#pragma unroll
            for (int kx = 0; kx < 5; ++kx) {
                float wv = sdw[c * 25 + ky * 5 + kx];
#pragma unroll
                for (int px = 0; px < 8; ++px) d[px] += wv * f[px + kx + 2];
            }
        }
#pragma unroll
        for (int oc = 0; oc < 8; ++oc) {
            float wm = spw[oc * 8 + c];
#pragma unroll
            for (int px = 0; px < 8; ++px) acc[oc][px] += wm * d[px];
        }
    }

#pragma unroll
    for (int oc = 0; oc < 8; ++oc) {
        union { bf16 h[8]; uint4 v; } pk;
#pragma unroll
        for (int px = 0; px < 8; ++px) pk.h[px] = f2b(acc[oc][px]);
        *(uint4*)(dw + ((size_t)b * QKV_CH + g * 8 + oc) * HW + y * 64 + x0) = pk.v;
    }
}

// K4a: kv partial accumulation. grid (NPG, 64, B)
__global__ __launch_bounds__(256) void k_kv(const bf16* __restrict__ qkv,
                                            const bf16* __restrict__ agg,
                                            float* __restrict__ part) {
    int tid = threadIdx.x;
    int lane = tid & 63, wv = tid >> 6;
    int pg = blockIdx.x, h = blockIdx.y, b = blockIdx.z;
    int cbase = 24 * h;
    const bf16* src = (h < 32)
        ? qkv + ((size_t)b * QKV_CH + cbase) * HW
        : agg + ((size_t)b * QKV_CH + (cbase - QKV_CH)) * HW;
    int p0 = pg * 1024 + tid * 4;

    float kf[8][4], vf[8][4];
#pragma unroll
    for (int d = 0; d < 8; ++d) {
        ushort4 u = *(const ushort4*)(src + (size_t)(8 + d) * HW + p0);
        kf[d][0] = fmaxf(u2f(u.x), 0.f);
        kf[d][1] = fmaxf(u2f(u.y), 0.f);
        kf[d][2] = fmaxf(u2f(u.z), 0.f);
        kf[d][3] = fmaxf(u2f(u.w), 0.f);
    }
#pragma unroll
    for (int e = 0; e < 8; ++e) {
        ushort4 u = *(const ushort4*)(src + (size_t)(16 + e) * HW + p0);
        vf[e][0] = u2f(u.x); vf[e][1] = u2f(u.y);
        vf[e][2] = u2f(u.z); vf[e][3] = u2f(u.w);
    }

    float acc[72];
#pragma unroll
    for (int i = 0; i < 72; ++i) acc[i] = 0.f;
#pragma unroll
    for (int j = 0; j < 4; ++j) {
#pragma unroll
        for (int d = 0; d < 8; ++d) {
#pragma unroll
            for (int e = 0; e < 8; ++e) acc[d * 9 + e] += kf[d][j] * vf[e][j];
            acc[d * 9 + 8] += kf[d][j];
        }
    }

#pragma unroll
    for (int m = 1; m < 64; m <<= 1) {
#pragma unroll
        for (int i = 0; i < 72; ++i) acc[i] += __shfl_xor(acc[i], m, 64);
    }

    float t0 = 0.f, t1 = 0.f;
#pragma unroll
    for (int i = 0; i < 64; ++i) t0 = (lane == i) ? acc[i] : t0;
#pragma unroll
    for (int i = 0; i < 8; ++i) t1 = (lane == i) ? acc[64 + i] : t1;

    int bh = b * 64 + h;
    float* pp = part + ((size_t)(bh * NPG + pg) * 4 + wv) * 72;
    pp[lane] = t0;
    if (lane < 8) pp[64 + lane] = t1;
}

// K4b: apply. grid (4, 64, B)
__global__ __launch_bounds__(256) void k_apply(const bf16* __restrict__ qkv,
                                               const bf16* __restrict__ agg,
                                               const float* __restrict__ part,
                                               float* __restrict__ out) {
    int tid = threadIdx.x;
    int pg = blockIdx.x, h = blockIdx.y, b = blockIdx.z;
    int bh = b * 64 + h;

    __shared__ float skv[72];
    if (tid < 72) {
        const float* pp = part + (size_t)bh * (NPG * 4) * 72 + tid;
        float s = 0.f;
#pragma unroll
        for (int j = 0; j < NPG * 4; ++j) s += pp[(size_t)j * 72];
        skv[tid] = s;
    }
    __syncthreads();

    int cbase = 24 * h;
    const bf16* src = (h < 32)
        ? qkv + ((size_t)b * QKV_CH + cbase) * HW
        : agg + ((size_t)b * QKV_CH + (cbase - QKV_CH)) * HW;
    int p0 = pg * 1024 + tid * 4;

    float qf[8][4];
#pragma unroll
    for (int d = 0; d < 8; ++d) {
        ushort4 u = *(const ushort4*)(src + (size_t)d * HW + p0);
        qf[d][0] = fmaxf(u2f(u.x), 0.f);
        qf[d][1] = fmaxf(u2f(u.y), 0.f);
        qf[d][2] = fmaxf(u2f(u.z), 0.f);
        qf[d][3] = fmaxf(u2f(u.w), 0.f);
    }

    float num[9][4];
#pragma unroll
    for (int e = 0; e < 9; ++e) {
#pragma unroll
        for (int j = 0; j < 4; ++j) {
            float s = 0.f;
#pragma unroll
            for (int d = 0; d < 8; ++d) s += qf[d][j] * skv[d * 9 + e];
            num[e][j] = s;
        }
    }
    float iv[4];
#pragma unroll
    for (int j = 0; j < 4; ++j) iv[j] = 1.f / (num[8][j] + 1e-15f);

#pragma unroll
    for (int e = 0; e < 8; ++e) {
        float4 r;
        r.x = num[e][0] * iv[0];
        r.y = num[e][1] * iv[1];
        r.z = num[e][2] * iv[2];
        r.w = num[e][3] * iv[3];
        *(float4*)(out + ((size_t)b * PROJ_IN + h * 8 + e) * HW + p0) = r;
    }
}

// K5: proj conv1x1 (256x512) + BN affine -> d_out fp32
// block 256 = 2 o-groups x 128 p-threads; tile 32 o x 512 p; micro 16o x 4p;
// c staged in 2 chunks of 256 (same reduction order as verified baseline).
__global__ __launch_bounds__(256) void k_proj(const float* __restrict__ attn,
                                              const float* __restrict__ w,
                                              const float* __restrict__ gamma,
                                              const float* __restrict__ beta,
                                              const float* __restrict__ mean,
                                              const float* __restrict__ var,
                                              float* __restrict__ out) {
    int tid = threadIdx.x;
    int to = tid >> 7, tp = tid & 127;
    int pg = blockIdx.x, og = blockIdx.y, b = blockIdx.z;

    __shared__ float sw[256 * 36];

    float acc[16][4];
#pragma unroll
    for (int j = 0; j < 16; ++j)
#pragma unroll
        for (int i = 0; i < 4; ++i) acc[j][i] = 0.f;

    const float* ap = attn + (size_t)b * PROJ_IN * HW + pg * 512 + tp * 4;

    for (int h = 0; h < 2; ++h) {
        __syncthreads();
        for (int i = tid; i < 32 * 256; i += 256) {
            int o = i >> 8, c = i & 255;
            sw[c * 36 + o] = w[(size_t)(og * 32 + o) * 512 + h * 256 + c];
        }
        __syncthreads();
#pragma unroll 4
        for (int c = 0; c < 256; ++c) {
            float4 xv = *(const float4*)(ap + (size_t)(h * 256 + c) * HW);
            const float* wr = &sw[c * 36 + to * 16];
            float4 w0 = *(const float4*)(wr);
            float4 w1 = *(const float4*)(wr + 4);
            float4 w2 = *(const float4*)(wr + 8);
            float4 w3 = *(const float4*)(wr + 12);
            float xs[4] = {xv.x, xv.y, xv.z, xv.w};
            float ws[16] = {w0.x, w0.y, w0.z, w0.w, w1.x, w1.y, w1.z, w1.w,
                            w2.x, w2.y, w2.z, w2.w, w3.x, w3.y, w3.z, w3.w};
#pragma unroll
            for (int j = 0; j < 16; ++j)
#pragma unroll
                for (int i = 0; i < 4; ++i) acc[j][i] += ws[j] * xs[i];
        }
    }

#pragma unroll
    for (int j = 0; j < 16; ++j) {
        int o = og * 32 + to * 16 + j;
        float inv = gamma[o] * rsqrtf(var[o] + 1e-5f);
        float add = beta[o] - mean[o] * inv;
        float4 r;
        r.x = acc[j][0] * inv + add;
        r.y = acc[j][1] * inv + add;
        r.z = acc[j][2] * inv + add;
        r.w = acc[j][3] * inv + add;
        *(float4*)(out + ((size_t)b * PROJ_OUT + o) * HW + pg * 512 + tp * 4) = r;
    }
}

extern "C" void kernel_launch(void* const* d_in, const int* in_sizes, int n_in,
                              void* d_out, int out_size, void* d_ws, size_t ws_size,
                              hipStream_t stream) {
    const float* x      = (const float*)d_in[0];
    const float* w_qkv  = (const float*)d_in[1];
    const float* w_dw   = (const float*)d_in[2];
    const float* w_pw   = (const float*)d_in[3];
    const float* w_proj = (const float*)d_in[4];
    const float* bn_g   = (const float*)d_in[5];
    const float* bn_b   = (const float*)d_in[6];
    const float* bn_m   = (const float*)d_in[7];
    const float* bn_v   = (const float*)d_in[8];
    float* out = (float*)d_out;

    char* ws = (char*)d_ws;
    bf16*  qkv  = (bf16*)(ws);                           // 48 MB
    bf16*  dwb  = (bf16*)(ws + (size_t)50331648);        // 48 MB
    float* attn = (float*)(ws + (size_t)100663296);      // 64 MB
    const size_t kMainWs = 167772160;                    // 160 MB
    const size_t kPartSz = (size_t)(B * 64) * NPG * 4 * 72 * sizeof(float);
    float* part = (ws_size >= kMainWs + kPartSz) ? (float*)(ws + kMainWs)
                                                 : (float*)d_out;

    dim3 blk(256);
    k_qkv  <<<dim3(8, 24, B), blk, 0, stream>>>(x, w_qkv, qkv);
    k_dwagg<<<dim3(2, 96, B), blk, 0, stream>>>(qkv, w_dw, w_pw, dwb);
    k_kv   <<<dim3(NPG, 64, B), blk, 0, stream>>>(qkv, dwb, part);
    k_apply<<<dim3(4, 64, B), blk, 0, stream>>>(qkv, dwb, part, attn);
    k_proj <<<dim3(8, 8, B), blk, 0, stream>>>(attn, w_proj, bn_g, bn_b, bn_m, bn_v, out);
}

// Round 11
// 472.612 us; speedup vs baseline: 2.1019x; 1.1382x over previous
//
#include <hip/hip_runtime.h>
#include <hip/hip_bf16.h>

using bf16 = __hip_bfloat16;

__device__ __forceinline__ float b2f(bf16 v) { return __bfloat162float(v); }
__device__ __forceinline__ bf16 f2b(float f) { return __float2bfloat16(f); }
__device__ __forceinline__ float u2f(unsigned short u) {
    return __uint_as_float(((unsigned)u) << 16);
}
// unpack a 32-bit word holding two bf16 (little-endian) to two floats
__device__ __forceinline__ void unpk(unsigned int w, float& a, float& b) {
    a = __uint_as_float(w << 16);
    b = __uint_as_float(w & 0xffff0000u);
}

#define B 8
#define CIN 256
#define HW 4096
#define QKV_CH 768
#define PROJ_IN 512
#define PROJ_OUT 256
#define NPG 4

// K1: qkv = w_qkv(768x256) @ x(b,256,4096) -> bf16
// block 256 = 2 o-groups x 128 p-threads; tile 32 o x 512 p; micro 16o x 4p.
// MO=16 keeps x L1 re-read traffic at 1.5 GB (<< FMA floor). Grid 1536 blocks;
// residency LDS-capped at 4 blocks/CU (16 waves/CU).
__global__ __launch_bounds__(256) void k_qkv(const float* __restrict__ x,
                                             const float* __restrict__ w,
                                             bf16* __restrict__ qkv) {
    int tid = threadIdx.x;
    int to = tid >> 7, tp = tid & 127;
    int pg = blockIdx.x, og = blockIdx.y, b = blockIdx.z;

    __shared__ float sw[256 * 36];  // sw[c*36 + o_local], 36 KB

    for (int i = tid; i < 32 * 256; i += 256) {
        int o = i >> 8, c = i & 255;
        sw[c * 36 + o] = w[(size_t)(og * 32 + o) * 256 + c];
    }
    __syncthreads();

    float acc[16][4];
#pragma unroll
    for (int j = 0; j < 16; ++j)
#pragma unroll
        for (int i = 0; i < 4; ++i) acc[j][i] = 0.f;

    const float* xp = x + (size_t)b * CIN * HW + pg * 512 + tp * 4;
#pragma unroll 4
    for (int c = 0; c < 256; ++c) {
        float4 xv = *(const float4*)(xp + (size_t)c * HW);
        const float* wr = &sw[c * 36 + to * 16];
        float4 w0 = *(const float4*)(wr);
        float4 w1 = *(const float4*)(wr + 4);
        float4 w2 = *(const float4*)(wr + 8);
        float4 w3 = *(const float4*)(wr + 12);
        float xs[4] = {xv.x, xv.y, xv.z, xv.w};
        float ws[16] = {w0.x, w0.y, w0.z, w0.w, w1.x, w1.y, w1.z, w1.w,
                        w2.x, w2.y, w2.z, w2.w, w3.x, w3.y, w3.z, w3.w};
#pragma unroll
        for (int j = 0; j < 16; ++j)
#pragma unroll
            for (int i = 0; i < 4; ++i) acc[j][i] += ws[j] * xs[i];
    }

#pragma unroll
    for (int j = 0; j < 16; ++j) {
        int o = og * 32 + to * 16 + j;
        union { bf16 h[4]; uint2 v; } pk;
#pragma unroll
        for (int i = 0; i < 4; ++i) pk.h[i] = f2b(acc[j][i]);
        *(uint2*)(qkv + ((size_t)b * QKV_CH + o) * HW + pg * 512 + tp * 4) = pk.v;
    }
}

// K2+K3 fused: depthwise 5x5 (pad 2) + group 8->8 pointwise mix. grid (2, 96, B)
__global__ __launch_bounds__(256) void k_dwagg(const bf16* __restrict__ qkv,
                                               const float* __restrict__ wdw,
                                               const float* __restrict__ wpw,
                                               bf16* __restrict__ dw) {
    int tid = threadIdx.x;
    int g = blockIdx.y, b = blockIdx.z;
    int x0 = (tid & 7) * 8;
    int y  = blockIdx.x * 32 + (tid >> 3);

    __shared__ float sdw[200];
    __shared__ float spw[64];
    if (tid < 200) sdw[tid] = wdw[(size_t)g * 200 + tid];
    if (tid < 64)  spw[tid] = wpw[(size_t)g * 64 + tid];
    __syncthreads();

    const bf16* src0 = qkv + ((size_t)b * QKV_CH + g * 8) * HW;

    float acc[8][8];
#pragma unroll
    for (int oc = 0; oc < 8; ++oc)
#pragma unroll
        for (int px = 0; px < 8; ++px) acc[oc][px] = 0.f;

#pragma unroll
    for (int c = 0; c < 8; ++c) {
        const bf16* src = src0 + (size_t)c * HW;
        float d[8];
#pragma unroll
        for (int px = 0; px < 8; ++px) d[px] = 0.f;

#pragma unroll
        for (int ky = 0; ky < 5; ++ky) {
            int yy = y + ky - 2;
            if (yy < 0 || yy > 63) continue;
            const bf16* row = src + yy * 64;
            float f[16];
            if (x0 > 0) {
                uint2 u = *(const uint2*)(row + x0 - 4);
                unpk(u.x, f[0], f[1]); unpk(u.y, f[2], f[3]);
            } else {
                f[0] = f[1] = f[2] = f[3] = 0.f;
            }
            uint4 m = *(const uint4*)(row + x0);
            unpk(m.x, f[4], f[5]);  unpk(m.y, f[6], f[7]);
            unpk(m.z, f[8], f[9]);  unpk(m.w, f[10], f[11]);
            if (x0 < 56) {
                uint2 u = *(const uint2*)(row + x0 + 8);
                unpk(u.x, f[12], f[13]); unpk(u.y, f[14], f[15]);
            } else {
                f[12] = f[13] = f[14] = f[15] = 0.f;
            }
#pragma unroll
            for (int kx = 0; kx < 5; ++kx) {
                float wv = sdw[c * 25 + ky * 5 + kx];
#pragma unroll
                for (int px = 0; px < 8; ++px) d[px] += wv * f[px + kx + 2];
            }
        }
#pragma unroll
        for (int oc = 0; oc < 8; ++oc) {
            float wm = spw[oc * 8 + c];
#pragma unroll
            for (int px = 0; px < 8; ++px) acc[oc][px] += wm * d[px];
        }
    }

#pragma unroll
    for (int oc = 0; oc < 8; ++oc) {
        union { bf16 h[8]; uint4 v; } pk;
#pragma unroll
        for (int px = 0; px < 8; ++px) pk.h[px] = f2b(acc[oc][px]);
        *(uint4*)(dw + ((size_t)b * QKV_CH + g * 8 + oc) * HW + y * 64 + x0) = pk.v;
    }
}

// K4a: kv partial accumulation. grid (NPG, 64, B)
__global__ __launch_bounds__(256) void k_kv(const bf16* __restrict__ qkv,
                                            const bf16* __restrict__ agg,
                                            float* __restrict__ part) {
    int tid = threadIdx.x;
    int lane = tid & 63, wv = tid >> 6;
    int pg = blockIdx.x, h = blockIdx.y, b = blockIdx.z;
    int cbase = 24 * h;
    const bf16* src = (h < 32)
        ? qkv + ((size_t)b * QKV_CH + cbase) * HW
        : agg + ((size_t)b * QKV_CH + (cbase - QKV_CH)) * HW;
    int p0 = pg * 1024 + tid * 4;

    float kf[8][4], vf[8][4];
#pragma unroll
    for (int d = 0; d < 8; ++d) {
        ushort4 u = *(const ushort4*)(src + (size_t)(8 + d) * HW + p0);
        kf[d][0] = fmaxf(u2f(u.x), 0.f);
        kf[d][1] = fmaxf(u2f(u.y), 0.f);
        kf[d][2] = fmaxf(u2f(u.z), 0.f);
        kf[d][3] = fmaxf(u2f(u.w), 0.f);
    }
#pragma unroll
    for (int e = 0; e < 8; ++e) {
        ushort4 u = *(const ushort4*)(src + (size_t)(16 + e) * HW + p0);
        vf[e][0] = u2f(u.x); vf[e][1] = u2f(u.y);
        vf[e][2] = u2f(u.z); vf[e][3] = u2f(u.w);
    }

    float acc[72];
#pragma unroll
    for (int i = 0; i < 72; ++i) acc[i] = 0.f;
#pragma unroll
    for (int j = 0; j < 4; ++j) {
#pragma unroll
        for (int d = 0; d < 8; ++d) {
#pragma unroll
            for (int e = 0; e < 8; ++e) acc[d * 9 + e] += kf[d][j] * vf[e][j];
            acc[d * 9 + 8] += kf[d][j];
        }
    }

#pragma unroll
    for (int m = 1; m < 64; m <<= 1) {
#pragma unroll
        for (int i = 0; i < 72; ++i) acc[i] += __shfl_xor(acc[i], m, 64);
    }

    float t0 = 0.f, t1 = 0.f;
#pragma unroll
    for (int i = 0; i < 64; ++i) t0 = (lane == i) ? acc[i] : t0;
#pragma unroll
    for (int i = 0; i < 8; ++i) t1 = (lane == i) ? acc[64 + i] : t1;

    int bh = b * 64 + h;
    float* pp = part + ((size_t)(bh * NPG + pg) * 4 + wv) * 72;
    pp[lane] = t0;
    if (lane < 8) pp[64 + lane] = t1;
}

// K4b: apply. grid (4, 64, B)
__global__ __launch_bounds__(256) void k_apply(const bf16* __restrict__ qkv,
                                               const bf16* __restrict__ agg,
                                               const float* __restrict__ part,
                                               float* __restrict__ out) {
    int tid = threadIdx.x;
    int pg = blockIdx.x, h = blockIdx.y, b = blockIdx.z;
    int bh = b * 64 + h;

    __shared__ float skv[72];
    if (tid < 72) {
        const float* pp = part + (size_t)bh * (NPG * 4) * 72 + tid;
        float s = 0.f;
#pragma unroll
        for (int j = 0; j < NPG * 4; ++j) s += pp[(size_t)j * 72];
        skv[tid] = s;
    }
    __syncthreads();

    int cbase = 24 * h;
    const bf16* src = (h < 32)
        ? qkv + ((size_t)b * QKV_CH + cbase) * HW
        : agg + ((size_t)b * QKV_CH + (cbase - QKV_CH)) * HW;
    int p0 = pg * 1024 + tid * 4;

    float qf[8][4];
#pragma unroll
    for (int d = 0; d < 8; ++d) {
        ushort4 u = *(const ushort4*)(src + (size_t)d * HW + p0);
        qf[d][0] = fmaxf(u2f(u.x), 0.f);
        qf[d][1] = fmaxf(u2f(u.y), 0.f);
        qf[d][2] = fmaxf(u2f(u.z), 0.f);
        qf[d][3] = fmaxf(u2f(u.w), 0.f);
    }

    float num[9][4];
#pragma unroll
    for (int e = 0; e < 9; ++e) {
#pragma unroll
        for (int j = 0; j < 4; ++j) {
            float s = 0.f;
#pragma unroll
            for (int d = 0; d < 8; ++d) s += qf[d][j] * skv[d * 9 + e];
            num[e][j] = s;
        }
    }
    float iv[4];
#pragma unroll
    for (int j = 0; j < 4; ++j) iv[j] = 1.f / (num[8][j] + 1e-15f);

#pragma unroll
    for (int e = 0; e < 8; ++e) {
        float4 r;
        r.x = num[e][0] * iv[0];
        r.y = num[e][1] * iv[1];
        r.z = num[e][2] * iv[2];
        r.w = num[e][3] * iv[3];
        *(float4*)(out + ((size_t)b * PROJ_IN + h * 8 + e) * HW + p0) = r;
    }
}

// K5: proj conv1x1 (256x512) + BN affine -> d_out fp32
// block 256 = 4 o-groups x 64 p-threads; tile 32 o x 256 p; micro 8o x 4p.
// MO=8 doubles grid to 1024 blocks = 4/CU (the 36KB-LDS residency cap,
// 16 waves/CU) -- round-10 counters showed MO=16's 512-block grid left the
// machine at 2 waves/SIMD (Occ 22%, VALUBusy 36%, 193us vs 109us FMA floor).
// x L1 re-read at MO=8: 32 x 67MB = 2.1 GB -> ~55us, still under FMA floor.
// Per-output c-order unchanged (h chunks of 256, sequential c) -> numerics
// bit-identical to the verified baseline.
__global__ __launch_bounds__(256) void k_proj(const float* __restrict__ attn,
                                              const float* __restrict__ w,
                                              const float* __restrict__ gamma,
                                              const float* __restrict__ beta,
                                              const float* __restrict__ mean,
                                              const float* __restrict__ var,
                                              float* __restrict__ out) {
    int tid = threadIdx.x;
    int to = tid >> 6, tp = tid & 63;
    int pg = blockIdx.x, og = blockIdx.y, b = blockIdx.z;

    __shared__ float sw[256 * 36];

    float acc[8][4];
#pragma unroll
    for (int j = 0; j < 8; ++j)
#pragma unroll
        for (int i = 0; i < 4; ++i) acc[j][i] = 0.f;

    const float* ap = attn + (size_t)b * PROJ_IN * HW + pg * 256 + tp * 4;

    for (int h = 0; h < 2; ++h) {
        __syncthreads();
        for (int i = tid; i < 32 * 256; i += 256) {
            int o = i >> 8, c = i & 255;
            sw[c * 36 + o] = w[(size_t)(og * 32 + o) * 512 + h * 256 + c];
        }
        __syncthreads();
#pragma unroll 4
        for (int c = 0; c < 256; ++c) {
            float4 xv = *(const float4*)(ap + (size_t)(h * 256 + c) * HW);
            const float* wr = &sw[c * 36 + to * 8];
            float4 w0 = *(const float4*)(wr);
            float4 w1 = *(const float4*)(wr + 4);
            float xs[4] = {xv.x, xv.y, xv.z, xv.w};
            float ws[8] = {w0.x, w0.y, w0.z, w0.w, w1.x, w1.y, w1.z, w1.w};
#pragma unroll
            for (int j = 0; j < 8; ++j)
#pragma unroll
                for (int i = 0; i < 4; ++i) acc[j][i] += ws[j] * xs[i];
        }
    }

#pragma unroll
    for (int j = 0; j < 8; ++j) {
        int o = og * 32 + to * 8 + j;
        float inv = gamma[o] * rsqrtf(var[o] + 1e-5f);
        float add = beta[o] - mean[o] * inv;
        float4 r;
        r.x = acc[j][0] * inv + add;
        r.y = acc[j][1] * inv + add;
        r.z = acc[j][2] * inv + add;
        r.w = acc[j][3] * inv + add;
        *(float4*)(out + ((size_t)b * PROJ_OUT + o) * HW + pg * 256 + tp * 4) = r;
    }
}

extern "C" void kernel_launch(void* const* d_in, const int* in_sizes, int n_in,
                              void* d_out, int out_size, void* d_ws, size_t ws_size,
                              hipStream_t stream) {
    const float* x      = (const float*)d_in[0];
    const float* w_qkv  = (const float*)d_in[1];
    const float* w_dw   = (const float*)d_in[2];
    const float* w_pw   = (const float*)d_in[3];
    const float* w_proj = (const float*)d_in[4];
    const float* bn_g   = (const float*)d_in[5];
    const float* bn_b   = (const float*)d_in[6];
    const float* bn_m   = (const float*)d_in[7];
    const float* bn_v   = (const float*)d_in[8];
    float* out = (float*)d_out;

    char* ws = (char*)d_ws;
    bf16*  qkv  = (bf16*)(ws);                           // 48 MB
    bf16*  dwb  = (bf16*)(ws + (size_t)50331648);        // 48 MB
    float* attn = (float*)(ws + (size_t)100663296);      // 64 MB
    const size_t kMainWs = 167772160;                    // 160 MB
    const size_t kPartSz = (size_t)(B * 64) * NPG * 4 * 72 * sizeof(float);
    float* part = (ws_size >= kMainWs + kPartSz) ? (float*)(ws + kMainWs)
                                                 : (float*)d_out;

    dim3 blk(256);
    k_qkv  <<<dim3(8, 24, B), blk, 0, stream>>>(x, w_qkv, qkv);
    k_dwagg<<<dim3(2, 96, B), blk, 0, stream>>>(qkv, w_dw, w_pw, dwb);
    k_kv   <<<dim3(NPG, 64, B), blk, 0, stream>>>(qkv, dwb, part);
    k_apply<<<dim3(4, 64, B), blk, 0, stream>>>(qkv, dwb, part, attn);
    k_proj <<<dim3(16, 8, B), blk, 0, stream>>>(attn, w_proj, bn_g, bn_b, bn_m, bn_v, out);
}